// Round 2
// baseline (725.234 us; speedup 1.0000x reference)
//
#include <hip/hip_runtime.h>
#include <hip/hip_cooperative_groups.h>

namespace cg = cooperative_groups;

namespace {

constexpr int B_  = 2;
constexpr int N_  = 512;
constexpr int IN_ = 512;
constexpr int M_  = 300;   // MEM
constexpr int H_  = 64;    // HID
constexpr float SLOPE_ = 0.01f;
constexpr int GRID_ = 768; // 3 blocks/CU, all-resident (cooperative)

// ---- workspace layout (float offsets). No atomics anywhere: every buffer is
// fully written by plain stores before it is read. ----
constexpr long OFF_W0AI = 0;                       // 512 x 64
constexpr long OFF_W0AJ = OFF_W0AI + 512L * 64;
constexpr long OFF_W1AI = OFF_W0AJ + 512L * 64;    // 300 x 64
constexpr long OFF_W1AJ = OFF_W1AI + 300L * 64;
constexpr long OFF_BSI0 = OFF_W1AJ + 300L * 64;    // 4 x 64 bias combos
constexpr long OFF_BSJ0 = OFF_BSI0 + 64;
constexpr long OFF_BSI1 = OFF_BSJ0 + 64;
constexpr long OFF_BSJ1 = OFF_BSI1 + 64;
constexpr long OFF_H0   = OFF_BSJ1 + 64;           // 1024 x 300 (summed)
constexpr long OFF_H0P  = OFF_H0   + 307200;       // 4 x (1024 x 300) partials
constexpr long OFF_SI0P = OFF_H0P  + 4L * 307200;  // 4 x (1024 x 64) partials
constexpr long OFF_SJ0P = OFF_SI0P + 4L * 65536;
constexpr long OFF_F1P  = OFF_SJ0P + 4L * 65536;   // 4 x (1024 x 300) partials
constexpr long OFF_H1   = OFF_F1P  + 4L * 307200;  // 1024 x 300
constexpr long OFF_SI1  = OFF_H1   + 307200;       // 1024 x 64
constexpr long OFF_SJ1  = OFF_SI1  + 65536;
constexpr long OFF_ZP0  = OFF_SJ1  + 65536;        // 2 x 256 softmax partials
constexpr long OFF_ZP1  = OFF_ZP0  + 512;
constexpr long OFF_P0   = OFF_ZP1  + 512;          // 2 x 512 x 512
constexpr long OFF_P1   = OFF_P0   + 2L * 512 * 512;  // total ~19.5 MB

__device__ __forceinline__ float4 f4add(float4 a, float4 b) {
    a.x += b.x; a.y += b.y; a.z += b.z; a.w += b.w; return a;
}

// ---------------------------------------------------------------------------
// One 32x64 GEMM tile (256 threads, 2x4 micro, TK=32, reg-prefetch staging).
//   C[slice] = scale * (sum_s A[s]) @ W + (slice==0 ? bias : 0)
// AFOLD: number of A partial buffers summed at load (stride afstride).
// split>1: K is sliced into whole 32-slabs; each slice writes its OWN buffer
// (C + slice*cslice) with plain stores — no atomics.
// ---------------------------------------------------------------------------
template<int AFOLD>
__device__ __forceinline__ void gemm_tile(
    const float* __restrict__ A, long afstride,
    const float* __restrict__ W, const float* __restrict__ bias,
    const float* __restrict__ Zp, float* __restrict__ C, long cslice,
    int K, int lda, int Cc, int R, int split, int local,
    float (*As)[38], float (*Ws)[64], float* zred)
{
    const int tx  = (Cc + 63) >> 6;
    const int ty  = (R + 31) >> 5;
    const int nrc = tx * ty;
    const int tile  = local % nrc;
    const int slice = local / nrc;
    const int row0 = (tile / tx) * 32;
    const int col0 = (tile % tx) * 64;
    const int nslab = (K + 31) >> 5;
    const int spl   = (nslab + split - 1) / split;
    const int kb    = slice * spl * 32;
    const int Ke    = min(K, kb + spl * 32);
    C += (long)slice * cslice;

    const int t   = threadIdx.x;
    const int ar  = t >> 3;
    const int ak  = (t & 7) * 4;
    const int arow = min(row0 + ar, R - 1);
    const int wk  = t >> 4;
    const int wc  = (t & 15) * 4;
    const int tm0 = (t >> 4) * 2;
    const int tn0 = (t & 15) * 4;

    auto loadA = [&](int k0) -> float4 {
        const int k = k0 + ak;
        const long base = (long)arow * lda + k;
        float4 r = make_float4(0.f, 0.f, 0.f, 0.f);
        if (k + 3 < Ke) {
            #pragma unroll
            for (int s = 0; s < AFOLD; ++s)
                r = f4add(r, *(const float4*)(A + (long)s * afstride + base));
        } else {
            #pragma unroll
            for (int u = 0; u < 4; ++u)
                if (k + u < Ke) {
                    float v = 0.f;
                    #pragma unroll
                    for (int s = 0; s < AFOLD; ++s)
                        v += A[(long)s * afstride + base + u];
                    (&r.x)[u] = v;
                }
        }
        return r;
    };
    auto loadW = [&](int k0, int s) -> float4 {
        const int gk = k0 + wk + 16 * s;
        if (gk < Ke) {
            const int c = col0 + wc;
            if (c + 3 < Cc) return *(const float4*)(W + (long)gk * Cc + c);
            float tv[4];
            #pragma unroll
            for (int u = 0; u < 4; ++u)
                tv[u] = (c + u < Cc) ? W[(long)gk * Cc + c + u] : 0.0f;
            return make_float4(tv[0], tv[1], tv[2], tv[3]);
        }
        return make_float4(0.f, 0.f, 0.f, 0.f);
    };

    float acc[2][4] = {};
    float4 av  = loadA(kb);
    float4 wv0 = loadW(kb, 0);
    float4 wv1 = loadW(kb, 1);

    for (int k0 = kb; k0 < Ke; k0 += 32) {
        As[ak + 0][ar] = av.x;
        As[ak + 1][ar] = av.y;
        As[ak + 2][ar] = av.z;
        As[ak + 3][ar] = av.w;
        *(float4*)&Ws[wk][wc]      = wv0;
        *(float4*)&Ws[wk + 16][wc] = wv1;
        __syncthreads();

        if (k0 + 32 < Ke) {
            av  = loadA(k0 + 32);
            wv0 = loadW(k0 + 32, 0);
            wv1 = loadW(k0 + 32, 1);
        }

        #pragma unroll
        for (int k = 0; k < 32; ++k) {
            const float a0 = As[k][tm0];
            const float a1 = As[k][tm0 + 1];
            const float4 w4 = *(const float4*)&Ws[k][tn0];
            acc[0][0] = fmaf(a0, w4.x, acc[0][0]);
            acc[0][1] = fmaf(a0, w4.y, acc[0][1]);
            acc[0][2] = fmaf(a0, w4.z, acc[0][2]);
            acc[0][3] = fmaf(a0, w4.w, acc[0][3]);
            acc[1][0] = fmaf(a1, w4.x, acc[1][0]);
            acc[1][1] = fmaf(a1, w4.y, acc[1][1]);
            acc[1][2] = fmaf(a1, w4.z, acc[1][2]);
            acc[1][3] = fmaf(a1, w4.w, acc[1][3]);
        }
        __syncthreads();
    }

    float scale = 1.0f;
    if (Zp != nullptr) {                   // cooperative softmax-denom reduce
        float v = Zp[t];
        #pragma unroll
        for (int off = 32; off > 0; off >>= 1)
            v += __shfl_down(v, off, 64);
        if ((t & 63) == 0) zred[t >> 6] = v;
        __syncthreads();
        scale = 1.0f / (zred[0] + zred[1] + zred[2] + zred[3]);
    }

    const int cbase = col0 + tn0;
    float bv[4] = {0.f, 0.f, 0.f, 0.f};
    if (bias != nullptr && slice == 0) {
        #pragma unroll
        for (int u = 0; u < 4; ++u)
            if (cbase + u < Cc) bv[u] = bias[cbase + u];
    }
    #pragma unroll
    for (int i = 0; i < 2; ++i) {
        const int r = row0 + tm0 + i;
        if (r < R) {
            if (cbase + 3 < Cc) {
                float4 o;
                o.x = fmaf(acc[i][0], scale, bv[0]);
                o.y = fmaf(acc[i][1], scale, bv[1]);
                o.z = fmaf(acc[i][2], scale, bv[2]);
                o.w = fmaf(acc[i][3], scale, bv[3]);
                *(float4*)(C + (long)r * Cc + cbase) = o;
            } else {
                #pragma unroll
                for (int u = 0; u < 4; ++u)
                    if (cbase + u < Cc)
                        C[(long)r * Cc + cbase + u] = fmaf(acc[i][u], scale, bv[u]);
            }
        }
    }
}

// ---------------------------------------------------------------------------
// Attention numerator tile (32i x 32j). FOLD: sum of si/sj partial buffers
// (stride fstride) folded into the LDS staging.
// ---------------------------------------------------------------------------
template<int FOLD>
__device__ __forceinline__ void attn_tile(
    const float* __restrict__ si, const float* __restrict__ sj, long fstride,
    const float* __restrict__ adj, const float* __restrict__ a2w,
    const float* __restrict__ a2b, float* __restrict__ p,
    float* __restrict__ Zpart, int g,
    float (*Si)[68], float (*Sj)[68], float* red)
{
    const int b    = g >> 8;
    const int tile = g & 255;
    const int i0 = (tile >> 4) * 32;
    const int j0 = (tile & 15) * 32;
    const int t  = threadIdx.x;

    {   // stage 32x64 tiles (summing FOLD partials)
        const int r  = t >> 3;
        const int hc = (t & 7) * 8;
        const long gib = ((long)(b * N_ + i0 + r)) * H_ + hc;
        const long gjb = ((long)(b * N_ + j0 + r)) * H_ + hc;
        float4 a0 = make_float4(0.f, 0.f, 0.f, 0.f);
        float4 a1 = a0, b0v = a0, b1v = a0;
        #pragma unroll
        for (int s = 0; s < FOLD; ++s) {
            const float* gi = si + (long)s * fstride + gib;
            const float* gj = sj + (long)s * fstride + gjb;
            a0  = f4add(a0,  *(const float4*)(gi));
            a1  = f4add(a1,  *(const float4*)(gi + 4));
            b0v = f4add(b0v, *(const float4*)(gj));
            b1v = f4add(b1v, *(const float4*)(gj + 4));
        }
        *(float4*)&Si[r][hc]     = a0;
        *(float4*)&Si[r][hc + 4] = a1;
        *(float4*)&Sj[r][hc]     = b0v;
        *(float4*)&Sj[r][hc + 4] = b1v;
    }
    __syncthreads();

    const int i  = t >> 3;
    const int jl = t & 7;

    float e[4] = {0.f, 0.f, 0.f, 0.f};
    #pragma unroll
    for (int h0 = 0; h0 < H_; h0 += 4) {
        const float4 a4 = *(const float4*)&Si[i][h0];
        const float w0v = a2w[h0 + 0];
        const float w1v = a2w[h0 + 1];
        const float w2v = a2w[h0 + 2];
        const float w3v = a2w[h0 + 3];
        #pragma unroll
        for (int u = 0; u < 4; ++u) {
            const float4 b4 = *(const float4*)&Sj[jl + 8 * u][h0];
            e[u] = fmaf(fmaxf(a4.x + b4.x, 0.f), w0v, e[u]);
            e[u] = fmaf(fmaxf(a4.y + b4.y, 0.f), w1v, e[u]);
            e[u] = fmaf(fmaxf(a4.z + b4.z, 0.f), w2v, e[u]);
            e[u] = fmaf(fmaxf(a4.w + b4.w, 0.f), w3v, e[u]);
        }
    }

    const float a2bv = a2b[0];
    const long rowbase = ((long)(b * N_ + i0 + i)) * N_ + j0 + jl;
    float lsum = 0.f;
    #pragma unroll
    for (int u = 0; u < 4; ++u) {
        float ev = e[u] + a2bv;
        ev = (ev >= 0.f) ? ev : SLOPE_ * ev;
        const float m  = adj[rowbase + 8 * u];
        const float pv = m * __expf(ev);
        p[rowbase + 8 * u] = pv;
        lsum += pv;
    }

    #pragma unroll
    for (int off = 32; off > 0; off >>= 1)
        lsum += __shfl_down(lsum, off, 64);
    if ((t & 63) == 0) red[t >> 6] = lsum;
    __syncthreads();
    if (t == 0)
        Zpart[b * 256 + tile] = red[0] + red[1] + red[2] + red[3];
}

// ---------------------------------------------------------------------------
// The fused cooperative kernel: 7 phases, 6 grid syncs, zero atomics.
// ---------------------------------------------------------------------------
__global__ __launch_bounds__(256, 3)
void fused_gat(const float* __restrict__ feature, const float* __restrict__ adj,
               const float* __restrict__ w0, const float* __restrict__ b0,
               const float* __restrict__ w1, const float* __restrict__ b1,
               const float* __restrict__ a1w, const float* __restrict__ a1b,
               const float* __restrict__ a2w, const float* __restrict__ a2b,
               float* __restrict__ out, float* __restrict__ ws)
{
    cg::grid_group grid = cg::this_grid();

    __shared__ __align__(16) float smem[32 * 68 * 2];  // union: GEMM / attn
    __shared__ float zred[8];
    float (*As)[38] = (float(*)[38])smem;
    float (*Ws)[64] = (float(*)[64])(smem + 32 * 38);
    float (*Si)[68] = (float(*)[68])smem;
    float (*Sj)[68] = (float(*)[68])(smem + 32 * 68);

    const float* Ai = a1w;                  // top half (300 x 64)
    const float* Aj = a1w + (long)M_ * H_;  // bottom half
    const int bx = blockIdx.x;
    const int G  = gridDim.x;

    // ---- Phase A: h0 partials (split 4) + layer-0 fused weights ----
    for (int g = bx; g < 674; g += G) {
        if (g < 640)
            gemm_tile<1>(feature, 0, w0, b0, nullptr, ws + OFF_H0P, 307200,
                         512, 512, 300, 1024, 4, g, As, Ws, zred);
        else if (g < 656)
            gemm_tile<1>(w0, 0, Ai, nullptr, nullptr, ws + OFF_W0AI, 0,
                         300, 300, 64, 512, 1, g - 640, As, Ws, zred);
        else if (g < 672)
            gemm_tile<1>(w0, 0, Aj, nullptr, nullptr, ws + OFF_W0AJ, 0,
                         300, 300, 64, 512, 1, g - 656, As, Ws, zred);
        else if (g == 672)
            gemm_tile<1>(b0, 0, Ai, nullptr, nullptr, ws + OFF_BSI0, 0,
                         300, 300, 64, 1, 1, 0, As, Ws, zred);
        else
            gemm_tile<1>(b0, 0, Aj, a1b, nullptr, ws + OFF_BSJ0, 0,
                         300, 300, 64, 1, 1, 0, As, Ws, zred);
    }
    grid.sync();

    // ---- Phase B: si0/sj0 partials (split 4) + layer-1 fused weights ----
    for (int g = bx; g < 278; g += G) {
        if (g < 128)
            gemm_tile<1>(feature, 0, ws + OFF_W0AI, ws + OFF_BSI0, nullptr,
                         ws + OFF_SI0P, 65536, 512, 512, 64, 1024, 4, g,
                         As, Ws, zred);
        else if (g < 256)
            gemm_tile<1>(feature, 0, ws + OFF_W0AJ, ws + OFF_BSJ0, nullptr,
                         ws + OFF_SJ0P, 65536, 512, 512, 64, 1024, 4, g - 128,
                         As, Ws, zred);
        else if (g < 266)
            gemm_tile<1>(w1, 0, Ai, nullptr, nullptr, ws + OFF_W1AI, 0,
                         300, 300, 64, 300, 1, g - 256, As, Ws, zred);
        else if (g < 276)
            gemm_tile<1>(w1, 0, Aj, nullptr, nullptr, ws + OFF_W1AJ, 0,
                         300, 300, 64, 300, 1, g - 266, As, Ws, zred);
        else if (g == 276)
            gemm_tile<1>(b1, 0, Ai, nullptr, nullptr, ws + OFF_BSI1, 0,
                         300, 300, 64, 1, 1, 0, As, Ws, zred);
        else
            gemm_tile<1>(b1, 0, Aj, a1b, nullptr, ws + OFF_BSJ1, 0,
                         300, 300, 64, 1, 1, 0, As, Ws, zred);
    }
    grid.sync();

    // ---- Phase C: attn layer 0 (blocks 0..511) | h0 partial-sum (rest) ----
    if (bx < 512) {
        attn_tile<4>(ws + OFF_SI0P, ws + OFF_SJ0P, 65536, adj, a2w, a2b,
                     ws + OFF_P0, ws + OFF_ZP0, bx, Si, Sj, zred);
    } else {
        const float4* s = (const float4*)(ws + OFF_H0P);
        float4* d = (float4*)(ws + OFF_H0);
        const int tid = (bx - 512) * 256 + threadIdx.x;
        const int nth = (G - 512) * 256;
        for (int i = tid; i < 76800; i += nth)
            d[i] = f4add(f4add(s[i], s[i + 76800]),
                         f4add(s[i + 2 * 76800], s[i + 3 * 76800]));
    }
    grid.sync();

    // ---- Phase D: f1 partials (split 4) = (1/Z0) * p0 @ h0 ----
    for (int g = bx; g < 640; g += G) {
        const int job   = g / 320;
        const int local = g % 320;
        gemm_tile<1>(ws + OFF_P0 + (long)job * 262144, 0,
                     ws + OFF_H0 + (long)job * 153600, nullptr,
                     ws + OFF_ZP0 + job * 256,
                     ws + OFF_F1P + (long)job * 153600, 307200,
                     512, 512, 300, 512, 4, local, As, Ws, zred);
    }
    grid.sync();

    // ---- Phase E: h1/si1/sj1 (A = sum of 4 f1 partials, folded at load) ----
    for (int g = bx; g < 224; g += G) {
        if (g < 160)
            gemm_tile<4>(ws + OFF_F1P, 307200, w1, b1, nullptr, ws + OFF_H1, 0,
                         300, 300, 300, 1024, 1, g, As, Ws, zred);
        else if (g < 192)
            gemm_tile<4>(ws + OFF_F1P, 307200, ws + OFF_W1AI, ws + OFF_BSI1,
                         nullptr, ws + OFF_SI1, 0,
                         300, 300, 64, 1024, 1, g - 160, As, Ws, zred);
        else
            gemm_tile<4>(ws + OFF_F1P, 307200, ws + OFF_W1AJ, ws + OFF_BSJ1,
                         nullptr, ws + OFF_SJ1, 0,
                         300, 300, 64, 1024, 1, g - 192, As, Ws, zred);
    }
    grid.sync();

    // ---- Phase F: attn layer 1 ----
    if (bx < 512)
        attn_tile<1>(ws + OFF_SI1, ws + OFF_SJ1, 0, adj, a2w, a2b,
                     ws + OFF_P1, ws + OFF_ZP1, bx, Si, Sj, zred);
    grid.sync();

    // ---- Phase G: out = (1/Z1) * p1 @ h1 ----
    for (int g = bx; g < 160; g += G) {
        const int job = g / 80;
        gemm_tile<1>(ws + OFF_P1 + (long)job * 262144, 0,
                     ws + OFF_H1 + (long)job * 153600, nullptr,
                     ws + OFF_ZP1 + job * 256,
                     out + (long)job * 153600, 0,
                     512, 512, 300, 512, 1, g % 80, As, Ws, zred);
    }
}

// ===========================================================================
// FALLBACK: round-0 multi-dispatch path (verbatim), used only if the
// cooperative launch is rejected (e.g. capture/residency limits).
// ===========================================================================
struct Jobs {
    const float* A[8]; const float* W[8]; const float* bias[8]; const float* Zp[8];
    float* C[8];
    int K[8]; int lda[8]; int Cc[8]; int R[8];
    int off[8]; int njobs;
};

__global__ __launch_bounds__(256)
void gemm_multi(Jobs jb)
{
    __shared__ __align__(16) float As[32][38];
    __shared__ __align__(16) float Ws[32][64];

    const int bid = blockIdx.x;
    int j = jb.njobs - 1;
    while (j > 0 && bid < jb.off[j]) --j;
    const int local = bid - jb.off[j];

    const float* __restrict__ A = jb.A[j];
    const float* __restrict__ W = jb.W[j];
    const float* bias = jb.bias[j];
    const float* Zp   = jb.Zp[j];
    float* __restrict__ C = jb.C[j];
    const int K = jb.K[j], lda = jb.lda[j], Cc = jb.Cc[j], R = jb.R[j];

    const int tx   = (Cc + 63) >> 6;
    const int row0 = (local / tx) * 32;
    const int col0 = (local % tx) * 64;

    const int t   = threadIdx.x;
    const int ar  = t >> 3;
    const int ak  = (t & 7) * 4;
    const int arow = min(row0 + ar, R - 1);
    const int wk  = t >> 4;
    const int wc  = (t & 15) * 4;
    const int tm0 = (t >> 4) * 2;
    const int tn0 = (t & 15) * 4;

    auto loadA = [&](int k0) -> float4 {
        const int k = k0 + ak;
        if (k + 3 < K) return *(const float4*)(A + (long)arow * lda + k);
        float tv[4];
        #pragma unroll
        for (int u = 0; u < 4; ++u)
            tv[u] = (k + u < K) ? A[(long)arow * lda + k + u] : 0.0f;
        return make_float4(tv[0], tv[1], tv[2], tv[3]);
    };
    auto loadW = [&](int k0, int s) -> float4 {
        const int gk = k0 + wk + 16 * s;
        if (gk < K) {
            const int c = col0 + wc;
            if (c + 3 < Cc) return *(const float4*)(W + (long)gk * Cc + c);
            float tv[4];
            #pragma unroll
            for (int u = 0; u < 4; ++u)
                tv[u] = (c + u < Cc) ? W[(long)gk * Cc + c + u] : 0.0f;
            return make_float4(tv[0], tv[1], tv[2], tv[3]);
        }
        return make_float4(0.f, 0.f, 0.f, 0.f);
    };

    float acc[2][4] = {};
    float4 av  = loadA(0);
    float4 wv0 = loadW(0, 0);
    float4 wv1 = loadW(0, 1);

    for (int k0 = 0; k0 < K; k0 += 32) {
        As[ak + 0][ar] = av.x;
        As[ak + 1][ar] = av.y;
        As[ak + 2][ar] = av.z;
        As[ak + 3][ar] = av.w;
        *(float4*)&Ws[wk][wc]      = wv0;
        *(float4*)&Ws[wk + 16][wc] = wv1;
        __syncthreads();

        if (k0 + 32 < K) {
            av  = loadA(k0 + 32);
            wv0 = loadW(k0 + 32, 0);
            wv1 = loadW(k0 + 32, 1);
        }

        #pragma unroll
        for (int k = 0; k < 32; ++k) {
            const float a0 = As[k][tm0];
            const float a1 = As[k][tm0 + 1];
            const float4 w4 = *(const float4*)&Ws[k][tn0];
            acc[0][0] = fmaf(a0, w4.x, acc[0][0]);
            acc[0][1] = fmaf(a0, w4.y, acc[0][1]);
            acc[0][2] = fmaf(a0, w4.z, acc[0][2]);
            acc[0][3] = fmaf(a0, w4.w, acc[0][3]);
            acc[1][0] = fmaf(a1, w4.x, acc[1][0]);
            acc[1][1] = fmaf(a1, w4.y, acc[1][1]);
            acc[1][2] = fmaf(a1, w4.z, acc[1][2]);
            acc[1][3] = fmaf(a1, w4.w, acc[1][3]);
        }
        __syncthreads();
    }

    float scale = 1.0f;
    if (Zp != nullptr) {
        float s0 = 0.f, s1 = 0.f, s2 = 0.f, s3 = 0.f;
        for (int u = 0; u < 256; u += 4) {
            s0 += Zp[u]; s1 += Zp[u + 1]; s2 += Zp[u + 2]; s3 += Zp[u + 3];
        }
        scale = 1.0f / ((s0 + s1) + (s2 + s3));
    }
    const int cbase = col0 + tn0;
    float bv[4] = {0.f, 0.f, 0.f, 0.f};
    if (bias != nullptr) {
        #pragma unroll
        for (int u = 0; u < 4; ++u)
            if (cbase + u < Cc) bv[u] = bias[cbase + u];
    }
    #pragma unroll
    for (int i = 0; i < 2; ++i) {
        const int r = row0 + tm0 + i;
        if (r < R) {
            if (cbase + 3 < Cc) {
                float4 o;
                o.x = fmaf(acc[i][0], scale, bv[0]);
                o.y = fmaf(acc[i][1], scale, bv[1]);
                o.z = fmaf(acc[i][2], scale, bv[2]);
                o.w = fmaf(acc[i][3], scale, bv[3]);
                *(float4*)(C + (long)r * Cc + cbase) = o;
            } else {
                #pragma unroll
                for (int u = 0; u < 4; ++u)
                    if (cbase + u < Cc)
                        C[(long)r * Cc + cbase + u] = fmaf(acc[i][u], scale, bv[u]);
            }
        }
    }
}

__global__ __launch_bounds__(256)
void attn_p_kernel(const float* __restrict__ si, const float* __restrict__ sj,
                   const float* __restrict__ adj, const float* __restrict__ a2w,
                   const float* __restrict__ a2b, float* __restrict__ p,
                   float* __restrict__ Zpart)
{
    __shared__ __align__(16) float Si[32][68];
    __shared__ __align__(16) float Sj[32][68];
    __shared__ float red[4];

    const int b  = blockIdx.z;
    const int i0 = blockIdx.y * 32;
    const int j0 = blockIdx.x * 32;
    const int t  = threadIdx.x;

    {
        const int r  = t >> 3;
        const int hc = (t & 7) * 8;
        const float* gi = si + ((long)(b * N_ + i0 + r)) * H_ + hc;
        const float* gj = sj + ((long)(b * N_ + j0 + r)) * H_ + hc;
        *(float4*)&Si[r][hc]     = *(const float4*)(gi);
        *(float4*)&Si[r][hc + 4] = *(const float4*)(gi + 4);
        *(float4*)&Sj[r][hc]     = *(const float4*)(gj);
        *(float4*)&Sj[r][hc + 4] = *(const float4*)(gj + 4);
    }
    __syncthreads();

    const int i  = t >> 3;
    const int jl = t & 7;

    float e[4] = {0.f, 0.f, 0.f, 0.f};
    #pragma unroll
    for (int h0 = 0; h0 < H_; h0 += 4) {
        const float4 a4 = *(const float4*)&Si[i][h0];
        const float w0v = a2w[h0 + 0];
        const float w1v = a2w[h0 + 1];
        const float w2v = a2w[h0 + 2];
        const float w3v = a2w[h0 + 3];
        #pragma unroll
        for (int u = 0; u < 4; ++u) {
            const float4 b4 = *(const float4*)&Sj[jl + 8 * u][h0];
            e[u] = fmaf(fmaxf(a4.x + b4.x, 0.f), w0v, e[u]);
            e[u] = fmaf(fmaxf(a4.y + b4.y, 0.f), w1v, e[u]);
            e[u] = fmaf(fmaxf(a4.z + b4.z, 0.f), w2v, e[u]);
            e[u] = fmaf(fmaxf(a4.w + b4.w, 0.f), w3v, e[u]);
        }
    }

    const float a2bv = a2b[0];
    const long rowbase = ((long)(b * N_ + i0 + i)) * N_ + j0 + jl;
    float lsum = 0.f;
    #pragma unroll
    for (int u = 0; u < 4; ++u) {
        float ev = e[u] + a2bv;
        ev = (ev >= 0.f) ? ev : SLOPE_ * ev;
        const float m  = adj[rowbase + 8 * u];
        const float pv = m * __expf(ev);
        p[rowbase + 8 * u] = pv;
        lsum += pv;
    }

    #pragma unroll
    for (int off = 32; off > 0; off >>= 1)
        lsum += __shfl_down(lsum, off, 64);
    if ((t & 63) == 0) red[t >> 6] = lsum;
    __syncthreads();
    if (t == 0)
        Zpart[b * 256 + blockIdx.y * 16 + blockIdx.x] =
            red[0] + red[1] + red[2] + red[3];
}

} // namespace

extern "C" void kernel_launch(void* const* d_in, const int* in_sizes, int n_in,
                              void* d_out, int out_size, void* d_ws, size_t ws_size,
                              hipStream_t stream)
{
    (void)in_sizes; (void)n_in; (void)out_size; (void)ws_size;
    const float* feature = (const float*)d_in[0];
    const float* adj     = (const float*)d_in[1];
    const float* w0      = (const float*)d_in[2];
    const float* b0      = (const float*)d_in[3];
    const float* w1      = (const float*)d_in[4];
    const float* b1      = (const float*)d_in[5];
    const float* a1w     = (const float*)d_in[6];   // (600, 64) row-major
    const float* a1b     = (const float*)d_in[7];
    const float* a2w     = (const float*)d_in[8];
    const float* a2b     = (const float*)d_in[9];
    float* out = (float*)d_out;
    float* ws  = (float*)d_ws;

    // ---- primary path: single fused cooperative kernel ----
    {
        void* args[] = {(void*)&feature, (void*)&adj, (void*)&w0, (void*)&b0,
                        (void*)&w1, (void*)&b1, (void*)&a1w, (void*)&a1b,
                        (void*)&a2w, (void*)&a2b, (void*)&out, (void*)&ws};
        hipError_t err = hipLaunchCooperativeKernel(
            (const void*)fused_gat, dim3(GRID_), dim3(256), args, 0, stream);
        if (err == hipSuccess) return;
        (void)hipGetLastError();   // clear sticky error; take fallback path
    }

    // ---- fallback: round-0 multi-dispatch path ----
    float* cW0Ai = ws + OFF_W0AI;
    float* cW0Aj = ws + OFF_W0AJ;
    float* cW1Ai = ws + OFF_W1AI;
    float* cW1Aj = ws + OFF_W1AJ;
    float* bsi0  = ws + OFF_BSI0;
    float* bsj0  = ws + OFF_BSJ0;
    float* bsi1  = ws + OFF_BSI1;
    float* bsj1  = ws + OFF_BSJ1;
    float* h0    = ws + OFF_H0;
    float* si0   = ws + OFF_SI0P;   // reuse partial slots as full buffers
    float* sj0   = ws + OFF_SJ0P;
    float* f1    = ws + OFF_F1P;
    float* h1    = ws + OFF_H1;
    float* si1   = ws + OFF_SI1;
    float* sj1   = ws + OFF_SJ1;
    float* Zp0   = ws + OFF_ZP0;
    float* Zp1   = ws + OFF_ZP1;
    float* p0    = ws + OFF_P0;
    float* p1    = ws + OFF_P1;

    const float* Ai = a1w;
    const float* Aj = a1w + (long)M_ * H_;

    auto set_job = [](Jobs& jb, int j, const float* A, const float* W,
                      const float* bias, const float* Zp, float* C,
                      int K, int lda, int Cc, int R, int& tiles) {
        jb.A[j] = A; jb.W[j] = W; jb.bias[j] = bias; jb.Zp[j] = Zp; jb.C[j] = C;
        jb.K[j] = K; jb.lda[j] = lda; jb.Cc[j] = Cc; jb.R[j] = R;
        jb.off[j] = tiles;
        tiles += ((R + 31) / 32) * ((Cc + 63) / 64);
    };

    {
        Jobs jb; int tiles = 0;
        set_job(jb, 0, w0, Ai, nullptr, nullptr, cW0Ai, M_, M_, H_, IN_, tiles);
        set_job(jb, 1, w0, Aj, nullptr, nullptr, cW0Aj, M_, M_, H_, IN_, tiles);
        set_job(jb, 2, w1, Ai, nullptr, nullptr, cW1Ai, M_, M_, H_, M_,  tiles);
        set_job(jb, 3, w1, Aj, nullptr, nullptr, cW1Aj, M_, M_, H_, M_,  tiles);
        set_job(jb, 4, b0, Ai, nullptr, nullptr, bsi0,  M_, M_, H_, 1,   tiles);
        set_job(jb, 5, b0, Aj, a1b,     nullptr, bsj0,  M_, M_, H_, 1,   tiles);
        set_job(jb, 6, b1, Ai, nullptr, nullptr, bsi1,  M_, M_, H_, 1,   tiles);
        set_job(jb, 7, b1, Aj, a1b,     nullptr, bsj1,  M_, M_, H_, 1,   tiles);
        jb.njobs = 8;
        gemm_multi<<<dim3(tiles), dim3(256), 0, stream>>>(jb);
    }
    {
        Jobs jb; int tiles = 0;
        set_job(jb, 0, feature, w0,    b0,   nullptr, h0,  IN_, IN_, M_, 1024, tiles);
        set_job(jb, 1, feature, cW0Ai, bsi0, nullptr, si0, IN_, IN_, H_, 1024, tiles);
        set_job(jb, 2, feature, cW0Aj, bsj0, nullptr, sj0, IN_, IN_, H_, 1024, tiles);
        jb.njobs = 3;
        gemm_multi<<<dim3(tiles), dim3(256), 0, stream>>>(jb);
    }
    attn_p_kernel<<<dim3(16, 16, B_), dim3(256), 0, stream>>>(
        si0, sj0, adj, a2w, a2b, p0, Zp0);
    {
        Jobs jb; int tiles = 0;
        set_job(jb, 0, p0,               h0,              nullptr, Zp0,       f1,
                N_, N_, M_, N_, tiles);
        set_job(jb, 1, p0 + (long)N_*N_, h0 + (long)N_*M_, nullptr, Zp0 + 256,
                f1 + (long)N_*M_, N_, N_, M_, N_, tiles);
        jb.njobs = 2;
        gemm_multi<<<dim3(tiles), dim3(256), 0, stream>>>(jb);
    }
    {
        Jobs jb; int tiles = 0;
        set_job(jb, 0, f1, w1,    b1,   nullptr, h1,  M_, M_, M_, 1024, tiles);
        set_job(jb, 1, f1, cW1Ai, bsi1, nullptr, si1, M_, M_, H_, 1024, tiles);
        set_job(jb, 2, f1, cW1Aj, bsj1, nullptr, sj1, M_, M_, H_, 1024, tiles);
        jb.njobs = 3;
        gemm_multi<<<dim3(tiles), dim3(256), 0, stream>>>(jb);
    }
    attn_p_kernel<<<dim3(16, 16, B_), dim3(256), 0, stream>>>(
        si1, sj1, adj, a2w, a2b, p1, Zp1);
    {
        Jobs jb; int tiles = 0;
        set_job(jb, 0, p1,               h1,              nullptr, Zp1,       out,
                N_, N_, M_, N_, tiles);
        set_job(jb, 1, p1 + (long)N_*N_, h1 + (long)N_*M_, nullptr, Zp1 + 256,
                out + (long)N_*M_, N_, N_, M_, N_, tiles);
        jb.njobs = 2;
        gemm_multi<<<dim3(tiles), dim3(256), 0, stream>>>(jb);
    }
}

// Round 3
// 174.630 us; speedup vs baseline: 4.1530x; 4.1530x over previous
//
#include <hip/hip_runtime.h>

namespace {

constexpr int B_  = 2;
constexpr int N_  = 512;
constexpr int IN_ = 512;
constexpr int M_  = 300;   // MEM
constexpr int H_  = 64;    // HID
constexpr float SLOPE_ = 0.01f;

// ---- workspace layout (float offsets). No atomics anywhere: every buffer is
// fully written by plain stores before it is read. ----
constexpr long OFF_W0AI = 0;                        // 512 x 64
constexpr long OFF_W0AJ = OFF_W0AI + 512L * 64;
constexpr long OFF_W1AI = OFF_W0AJ + 512L * 64;     // 300 x 64
constexpr long OFF_W1AJ = OFF_W1AI + 300L * 64;
constexpr long OFF_BSI0 = OFF_W1AJ + 300L * 64;     // 4 x 64 bias combos
constexpr long OFF_BSJ0 = OFF_BSI0 + 64;
constexpr long OFF_BSI1 = OFF_BSJ0 + 64;
constexpr long OFF_BSJ1 = OFF_BSI1 + 64;
constexpr long OFF_H0   = OFF_BSJ1 + 64;            // 1024 x 300 (summed)
constexpr long OFF_H0P  = OFF_H0   + 307200;        // 2 x (1024 x 300) partials
constexpr long OFF_SI0P = OFF_H0P  + 2L * 307200;   // 4 x (1024 x 64) partials
constexpr long OFF_SJ0P = OFF_SI0P + 4L * 65536;
constexpr long OFF_F1P  = OFF_SJ0P + 4L * 65536;    // 4 x (1024 x 300) partials
constexpr long OFF_H1   = OFF_F1P  + 4L * 307200;   // 1024 x 300 (summed)
constexpr long OFF_H1P  = OFF_H1   + 307200;        // 2 x (1024 x 300) partials
constexpr long OFF_SI1P = OFF_H1P  + 2L * 307200;   // 2 x (1024 x 64) partials
constexpr long OFF_SJ1P = OFF_SI1P + 2L * 65536;
constexpr long OFF_ZP0  = OFF_SJ1P + 2L * 65536;    // 2 x 256 softmax partials
constexpr long OFF_ZP1  = OFF_ZP0  + 512;
constexpr long OFF_P0   = OFF_ZP1  + 512;           // 2 x 512 x 512
constexpr long OFF_P1   = OFF_P0   + 2L * 512 * 512;  // total ~20 MB

__device__ __forceinline__ float4 f4add(float4 a, float4 b) {
    a.x += b.x; a.y += b.y; a.z += b.z; a.w += b.w; return a;
}

// ---------------------------------------------------------------------------
// One 32x64 GEMM tile (256 threads, 2x4 micro, TK=32, reg-prefetch staging).
//   C[slice] = scale * (sum_s A[s]) @ W + (slice==0 ? bias : 0)
// AFOLD: number of A partial buffers summed at load (stride afstride).
// split>1: K sliced into whole 32-slabs; each slice writes its OWN buffer
// (C + slice*cslice) with plain stores — no atomics.
// Zp non-null: scale = 1/sum(Zp[0..255]) via cooperative shuffle reduce.
// (This device function + attn_tile validated end-to-end in round 2.)
// ---------------------------------------------------------------------------
template<int AFOLD>
__device__ __forceinline__ void gemm_tile(
    const float* __restrict__ A, long afstride,
    const float* __restrict__ W, const float* __restrict__ bias,
    const float* __restrict__ Zp, float* __restrict__ C, long cslice,
    int K, int lda, int Cc, int R, int split, int local,
    float (*As)[38], float (*Ws)[64], float* zred)
{
    const int tx  = (Cc + 63) >> 6;
    const int ty  = (R + 31) >> 5;
    const int nrc = tx * ty;
    const int tile  = local % nrc;
    const int slice = local / nrc;
    const int row0 = (tile / tx) * 32;
    const int col0 = (tile % tx) * 64;
    const int nslab = (K + 31) >> 5;
    const int spl   = (nslab + split - 1) / split;
    const int kb    = slice * spl * 32;
    const int Ke    = min(K, kb + spl * 32);
    C += (long)slice * cslice;

    const int t   = threadIdx.x;
    const int ar  = t >> 3;
    const int ak  = (t & 7) * 4;
    const int arow = min(row0 + ar, R - 1);
    const int wk  = t >> 4;
    const int wc  = (t & 15) * 4;
    const int tm0 = (t >> 4) * 2;
    const int tn0 = (t & 15) * 4;

    auto loadA = [&](int k0) -> float4 {
        const int k = k0 + ak;
        const long base = (long)arow * lda + k;
        float4 r = make_float4(0.f, 0.f, 0.f, 0.f);
        if (k + 3 < Ke) {
            #pragma unroll
            for (int s = 0; s < AFOLD; ++s)
                r = f4add(r, *(const float4*)(A + (long)s * afstride + base));
        } else {
            #pragma unroll
            for (int u = 0; u < 4; ++u)
                if (k + u < Ke) {
                    float v = 0.f;
                    #pragma unroll
                    for (int s = 0; s < AFOLD; ++s)
                        v += A[(long)s * afstride + base + u];
                    (&r.x)[u] = v;
                }
        }
        return r;
    };
    auto loadW = [&](int k0, int s) -> float4 {
        const int gk = k0 + wk + 16 * s;
        if (gk < Ke) {
            const int c = col0 + wc;
            if (c + 3 < Cc) return *(const float4*)(W + (long)gk * Cc + c);
            float tv[4];
            #pragma unroll
            for (int u = 0; u < 4; ++u)
                tv[u] = (c + u < Cc) ? W[(long)gk * Cc + c + u] : 0.0f;
            return make_float4(tv[0], tv[1], tv[2], tv[3]);
        }
        return make_float4(0.f, 0.f, 0.f, 0.f);
    };

    float acc[2][4] = {};
    float4 av  = loadA(kb);
    float4 wv0 = loadW(kb, 0);
    float4 wv1 = loadW(kb, 1);

    for (int k0 = kb; k0 < Ke; k0 += 32) {
        As[ak + 0][ar] = av.x;
        As[ak + 1][ar] = av.y;
        As[ak + 2][ar] = av.z;
        As[ak + 3][ar] = av.w;
        *(float4*)&Ws[wk][wc]      = wv0;
        *(float4*)&Ws[wk + 16][wc] = wv1;
        __syncthreads();

        if (k0 + 32 < Ke) {
            av  = loadA(k0 + 32);
            wv0 = loadW(k0 + 32, 0);
            wv1 = loadW(k0 + 32, 1);
        }

        #pragma unroll
        for (int k = 0; k < 32; ++k) {
            const float a0 = As[k][tm0];
            const float a1 = As[k][tm0 + 1];
            const float4 w4 = *(const float4*)&Ws[k][tn0];
            acc[0][0] = fmaf(a0, w4.x, acc[0][0]);
            acc[0][1] = fmaf(a0, w4.y, acc[0][1]);
            acc[0][2] = fmaf(a0, w4.z, acc[0][2]);
            acc[0][3] = fmaf(a0, w4.w, acc[0][3]);
            acc[1][0] = fmaf(a1, w4.x, acc[1][0]);
            acc[1][1] = fmaf(a1, w4.y, acc[1][1]);
            acc[1][2] = fmaf(a1, w4.z, acc[1][2]);
            acc[1][3] = fmaf(a1, w4.w, acc[1][3]);
        }
        __syncthreads();
    }

    float scale = 1.0f;
    if (Zp != nullptr) {                   // cooperative softmax-denom reduce
        float v = Zp[t];
        #pragma unroll
        for (int off = 32; off > 0; off >>= 1)
            v += __shfl_down(v, off, 64);
        if ((t & 63) == 0) zred[t >> 6] = v;
        __syncthreads();
        scale = 1.0f / (zred[0] + zred[1] + zred[2] + zred[3]);
    }

    const int cbase = col0 + tn0;
    float bv[4] = {0.f, 0.f, 0.f, 0.f};
    if (bias != nullptr && slice == 0) {
        #pragma unroll
        for (int u = 0; u < 4; ++u)
            if (cbase + u < Cc) bv[u] = bias[cbase + u];
    }
    #pragma unroll
    for (int i = 0; i < 2; ++i) {
        const int r = row0 + tm0 + i;
        if (r < R) {
            if (cbase + 3 < Cc) {
                float4 o;
                o.x = fmaf(acc[i][0], scale, bv[0]);
                o.y = fmaf(acc[i][1], scale, bv[1]);
                o.z = fmaf(acc[i][2], scale, bv[2]);
                o.w = fmaf(acc[i][3], scale, bv[3]);
                *(float4*)(C + (long)r * Cc + cbase) = o;
            } else {
                #pragma unroll
                for (int u = 0; u < 4; ++u)
                    if (cbase + u < Cc)
                        C[(long)r * Cc + cbase + u] = fmaf(acc[i][u], scale, bv[u]);
            }
        }
    }
}

// ---------------------------------------------------------------------------
// Multi-job GEMM dispatcher: blockIdx.x -> (job, slice, tile).
// ---------------------------------------------------------------------------
struct JobsK {
    const float* A[8]; long afstride[8];
    const float* W[8]; const float* bias[8]; const float* Zp[8];
    float* C[8]; long cslice[8];
    int K[8]; int lda[8]; int Cc[8]; int R[8]; int split[8];
    int off[8]; int njobs;
};

template<int AFOLD>
__global__ __launch_bounds__(256)
void gemm_jobs(JobsK jb)
{
    __shared__ __align__(16) float As[32][38];
    __shared__ __align__(16) float Ws[32][64];
    __shared__ float zred[4];

    const int bid = blockIdx.x;
    int j = jb.njobs - 1;
    while (j > 0 && bid < jb.off[j]) --j;
    const int local = bid - jb.off[j];

    gemm_tile<AFOLD>(jb.A[j], jb.afstride[j], jb.W[j], jb.bias[j], jb.Zp[j],
                     jb.C[j], jb.cslice[j], jb.K[j], jb.lda[j], jb.Cc[j],
                     jb.R[j], jb.split[j], local, As, Ws, zred);
}

// ---------------------------------------------------------------------------
// Attention numerator tile (32i x 32j). FOLD: sum of si/sj partial buffers
// (stride fstride in floats) folded into the LDS staging.
// ---------------------------------------------------------------------------
template<int FOLD>
__device__ __forceinline__ void attn_tile(
    const float* __restrict__ si, const float* __restrict__ sj, long fstride,
    const float* __restrict__ adj, const float* __restrict__ a2w,
    const float* __restrict__ a2b, float* __restrict__ p,
    float* __restrict__ Zpart, int g,
    float (*Si)[68], float (*Sj)[68], float* red)
{
    const int b    = g >> 8;
    const int tile = g & 255;
    const int i0 = (tile >> 4) * 32;
    const int j0 = (tile & 15) * 32;
    const int t  = threadIdx.x;

    {   // stage 32x64 tiles (summing FOLD partials)
        const int r  = t >> 3;
        const int hc = (t & 7) * 8;
        const long gib = ((long)(b * N_ + i0 + r)) * H_ + hc;
        const long gjb = ((long)(b * N_ + j0 + r)) * H_ + hc;
        float4 a0 = make_float4(0.f, 0.f, 0.f, 0.f);
        float4 a1 = a0, b0v = a0, b1v = a0;
        #pragma unroll
        for (int s = 0; s < FOLD; ++s) {
            const float* gi = si + (long)s * fstride + gib;
            const float* gj = sj + (long)s * fstride + gjb;
            a0  = f4add(a0,  *(const float4*)(gi));
            a1  = f4add(a1,  *(const float4*)(gi + 4));
            b0v = f4add(b0v, *(const float4*)(gj));
            b1v = f4add(b1v, *(const float4*)(gj + 4));
        }
        *(float4*)&Si[r][hc]     = a0;
        *(float4*)&Si[r][hc + 4] = a1;
        *(float4*)&Sj[r][hc]     = b0v;
        *(float4*)&Sj[r][hc + 4] = b1v;
    }
    __syncthreads();

    const int i  = t >> 3;
    const int jl = t & 7;

    float e[4] = {0.f, 0.f, 0.f, 0.f};
    #pragma unroll
    for (int h0 = 0; h0 < H_; h0 += 4) {
        const float4 a4 = *(const float4*)&Si[i][h0];
        const float w0v = a2w[h0 + 0];
        const float w1v = a2w[h0 + 1];
        const float w2v = a2w[h0 + 2];
        const float w3v = a2w[h0 + 3];
        #pragma unroll
        for (int u = 0; u < 4; ++u) {
            const float4 b4 = *(const float4*)&Sj[jl + 8 * u][h0];
            e[u] = fmaf(fmaxf(a4.x + b4.x, 0.f), w0v, e[u]);
            e[u] = fmaf(fmaxf(a4.y + b4.y, 0.f), w1v, e[u]);
            e[u] = fmaf(fmaxf(a4.z + b4.z, 0.f), w2v, e[u]);
            e[u] = fmaf(fmaxf(a4.w + b4.w, 0.f), w3v, e[u]);
        }
    }

    const float a2bv = a2b[0];
    const long rowbase = ((long)(b * N_ + i0 + i)) * N_ + j0 + jl;
    float lsum = 0.f;
    #pragma unroll
    for (int u = 0; u < 4; ++u) {
        float ev = e[u] + a2bv;
        ev = (ev >= 0.f) ? ev : SLOPE_ * ev;
        const float m  = adj[rowbase + 8 * u];
        const float pv = m * __expf(ev);
        p[rowbase + 8 * u] = pv;
        lsum += pv;
    }

    #pragma unroll
    for (int off = 32; off > 0; off >>= 1)
        lsum += __shfl_down(lsum, off, 64);
    if ((t & 63) == 0) red[t >> 6] = lsum;
    __syncthreads();
    if (t == 0)
        Zpart[b * 256 + tile] = red[0] + red[1] + red[2] + red[3];
}

// ---------------------------------------------------------------------------
// Attention dispatch: blocks 0..511 compute p/Zpart (folding FOLD si/sj
// partials); blocks 512..767 sum the 2 h-partials into the final h buffer
// (h is needed by the NEXT dispatch as the GEMM W operand).
// ---------------------------------------------------------------------------
template<int FOLD>
__global__ __launch_bounds__(256)
void attn_fused(const float* __restrict__ si, const float* __restrict__ sj,
                const float* __restrict__ adj, const float* __restrict__ a2w,
                const float* __restrict__ a2b, float* __restrict__ p,
                float* __restrict__ Zpart,
                const float4* __restrict__ hsrc, float4* __restrict__ hdst)
{
    __shared__ __align__(16) float Si[32][68];
    __shared__ __align__(16) float Sj[32][68];
    __shared__ float red[4];

    const int bx = blockIdx.x;
    if (bx < 512) {
        attn_tile<FOLD>(si, sj, 65536, adj, a2w, a2b, p, Zpart, bx,
                        Si, Sj, red);
    } else {
        // sum 2 x (1024x300) partials: 76800 float4, 65536 threads
        const int tid = (bx - 512) * 256 + threadIdx.x;
        for (int i = tid; i < 76800; i += 65536)
            hdst[i] = f4add(hsrc[i], hsrc[i + 76800]);
    }
}

} // namespace

extern "C" void kernel_launch(void* const* d_in, const int* in_sizes, int n_in,
                              void* d_out, int out_size, void* d_ws, size_t ws_size,
                              hipStream_t stream)
{
    (void)in_sizes; (void)n_in; (void)out_size; (void)ws_size;
    const float* feature = (const float*)d_in[0];
    const float* adj     = (const float*)d_in[1];
    const float* w0      = (const float*)d_in[2];
    const float* b0      = (const float*)d_in[3];
    const float* w1      = (const float*)d_in[4];
    const float* b1      = (const float*)d_in[5];
    const float* a1w     = (const float*)d_in[6];   // (600, 64) row-major
    const float* a1b     = (const float*)d_in[7];
    const float* a2w     = (const float*)d_in[8];
    const float* a2b     = (const float*)d_in[9];
    float* out = (float*)d_out;
    float* ws  = (float*)d_ws;

    float* cW0Ai = ws + OFF_W0AI;
    float* cW0Aj = ws + OFF_W0AJ;
    float* cW1Ai = ws + OFF_W1AI;
    float* cW1Aj = ws + OFF_W1AJ;
    float* bsi0  = ws + OFF_BSI0;
    float* bsj0  = ws + OFF_BSJ0;
    float* bsi1  = ws + OFF_BSI1;
    float* bsj1  = ws + OFF_BSJ1;
    float* h0    = ws + OFF_H0;
    float* h0p   = ws + OFF_H0P;
    float* si0p  = ws + OFF_SI0P;
    float* sj0p  = ws + OFF_SJ0P;
    float* f1p   = ws + OFF_F1P;
    float* h1    = ws + OFF_H1;
    float* h1p   = ws + OFF_H1P;
    float* si1p  = ws + OFF_SI1P;
    float* sj1p  = ws + OFF_SJ1P;
    float* Zp0   = ws + OFF_ZP0;
    float* Zp1   = ws + OFF_ZP1;
    float* p0    = ws + OFF_P0;
    float* p1    = ws + OFF_P1;

    const float* Ai = a1w;                    // top half (300 x 64)
    const float* Aj = a1w + (long)M_ * H_;    // bottom half

    auto set_job = [](JobsK& jb, int j, const float* A, long afstride,
                      const float* W, const float* bias, const float* Zp,
                      float* C, long cslice, int K, int lda, int Cc, int R,
                      int split, int& tiles) {
        jb.A[j] = A; jb.afstride[j] = afstride;
        jb.W[j] = W; jb.bias[j] = bias; jb.Zp[j] = Zp;
        jb.C[j] = C; jb.cslice[j] = cslice;
        jb.K[j] = K; jb.lda[j] = lda; jb.Cc[j] = Cc; jb.R[j] = R;
        jb.split[j] = split;
        jb.off[j] = tiles;
        tiles += ((R + 31) / 32) * ((Cc + 63) / 64) * split;
    };

    // ---- D1: fused attention-projection weights + bias combos (56 blocks) ----
    {
        JobsK jb; int tiles = 0;
        set_job(jb, 0, w0, 0, Ai, nullptr, nullptr, cW0Ai, 0, M_, M_, H_, IN_, 1, tiles);
        set_job(jb, 1, w0, 0, Aj, nullptr, nullptr, cW0Aj, 0, M_, M_, H_, IN_, 1, tiles);
        set_job(jb, 2, w1, 0, Ai, nullptr, nullptr, cW1Ai, 0, M_, M_, H_, M_,  1, tiles);
        set_job(jb, 3, w1, 0, Aj, nullptr, nullptr, cW1Aj, 0, M_, M_, H_, M_,  1, tiles);
        set_job(jb, 4, b0, 0, Ai, nullptr, nullptr, bsi0,  0, M_, M_, H_, 1,   1, tiles);
        set_job(jb, 5, b0, 0, Aj, a1b,     nullptr, bsj0,  0, M_, M_, H_, 1,   1, tiles);
        set_job(jb, 6, b1, 0, Ai, nullptr, nullptr, bsi1,  0, M_, M_, H_, 1,   1, tiles);
        set_job(jb, 7, b1, 0, Aj, a1b,     nullptr, bsj1,  0, M_, M_, H_, 1,   1, tiles);
        jb.njobs = 8;
        gemm_jobs<1><<<dim3(tiles), dim3(256), 0, stream>>>(jb);
    }

    // ---- D2: layer-0 projections, split-K partials (576 blocks) ----
    {
        JobsK jb; int tiles = 0;
        set_job(jb, 0, feature, 0, w0,    b0,   nullptr, h0p,  307200,
                IN_, IN_, M_, 1024, 2, tiles);                       // 320
        set_job(jb, 1, feature, 0, cW0Ai, bsi0, nullptr, si0p, 65536,
                IN_, IN_, H_, 1024, 4, tiles);                       // 128
        set_job(jb, 2, feature, 0, cW0Aj, bsj0, nullptr, sj0p, 65536,
                IN_, IN_, H_, 1024, 4, tiles);                       // 128
        jb.njobs = 3;
        gemm_jobs<1><<<dim3(tiles), dim3(256), 0, stream>>>(jb);
    }

    // ---- D3: p0 + Zpart0 (fold 4 si/sj partials) | h0 sum (768 blocks) ----
    attn_fused<4><<<dim3(768), dim3(256), 0, stream>>>(
        si0p, sj0p, adj, a2w, a2b, p0, Zp0, (const float4*)h0p, (float4*)h0);

    // ---- D4: f1 partials (split 4) = (1/Z0) * p0 @ h0 (640 blocks) ----
    {
        JobsK jb; int tiles = 0;
        set_job(jb, 0, p0, 0, h0, nullptr, Zp0, f1p, 307200,
                N_, N_, M_, N_, 4, tiles);                           // 320
        set_job(jb, 1, p0 + (long)N_*N_, 0, h0 + (long)N_*M_, nullptr,
                Zp0 + 256, f1p + (long)N_*M_, 307200,
                N_, N_, M_, N_, 4, tiles);                           // 320
        jb.njobs = 2;
        gemm_jobs<1><<<dim3(tiles), dim3(256), 0, stream>>>(jb);
    }

    // ---- D5: layer-1 projections, A = sum of 4 f1 partials (448 blocks) ----
    {
        JobsK jb; int tiles = 0;
        set_job(jb, 0, f1p, 307200, w1,    b1,   nullptr, h1p,  307200,
                M_, M_, M_, 1024, 2, tiles);                         // 320
        set_job(jb, 1, f1p, 307200, cW1Ai, bsi1, nullptr, si1p, 65536,
                M_, M_, H_, 1024, 2, tiles);                         // 64
        set_job(jb, 2, f1p, 307200, cW1Aj, bsj1, nullptr, sj1p, 65536,
                M_, M_, H_, 1024, 2, tiles);                         // 64
        jb.njobs = 3;
        gemm_jobs<4><<<dim3(tiles), dim3(256), 0, stream>>>(jb);
    }

    // ---- D6: p1 + Zpart1 (fold 2) | h1 sum (768 blocks) ----
    attn_fused<2><<<dim3(768), dim3(256), 0, stream>>>(
        si1p, sj1p, adj, a2w, a2b, p1, Zp1, (const float4*)h1p, (float4*)h1);

    // ---- D7: out = (1/Z1) * p1 @ h1 (160 blocks) ----
    {
        JobsK jb; int tiles = 0;
        set_job(jb, 0, p1, 0, h1, nullptr, Zp1, out, 0,
                N_, N_, M_, N_, 1, tiles);                           // 80
        set_job(jb, 1, p1 + (long)N_*N_, 0, h1 + (long)N_*M_, nullptr,
                Zp1 + 256, out + (long)N_*M_, 0,
                N_, N_, M_, N_, 1, tiles);                           // 80
        jb.njobs = 2;
        gemm_jobs<1><<<dim3(tiles), dim3(256), 0, stream>>>(jb);
    }
}